// Round 1
// baseline (6092.082 us; speedup 1.0000x reference)
//
#include <hip/hip_runtime.h>

#define Bdim 64
#define Hdim 1024
#define Vdim 32000
#define Tdim 40
#define KC 64

// Order-preserving float->uint32 map; pack with (0xFFFFFFFF - v) so that
// u64 max == (max value, lowest index on exact ties) — matches np.argmax.
__device__ __forceinline__ unsigned long long pack_key(float f, int v) {
    unsigned u = __float_as_uint(f);
    u = (u & 0x80000000u) ? ~u : (u | 0x80000000u);
    return ((unsigned long long)u << 32) | (unsigned long long)(0xFFFFFFFFu - (unsigned)v);
}

// C[b][v] = sum_k hin[b*hstride + k] * w_out[v*H + k] + b_out[v]
// tile: 128 v x 64 b per block, 256 threads, micro-tile 8v x 4b.
__global__ __launch_bounds__(256, 2)
void k_logits(const float* __restrict__ hin, int hstride,
              const float* __restrict__ w_out, const float* __restrict__ b_out,
              float* __restrict__ dec_out, int t_out,
              unsigned long long* __restrict__ slots, int do_argmax)
{
    __shared__ float Ws[128][68];
    __shared__ float As[64][68];
    __shared__ unsigned long long red[256][4];

    const int tid = threadIdx.x;
    const int tx = tid & 15;        // v dimension
    const int ty = tid >> 4;        // b dimension (0..15)
    const int vb = blockIdx.x * 128;

    float acc[4][8];
#pragma unroll
    for (int j = 0; j < 4; j++)
#pragma unroll
        for (int r = 0; r < 8; r++) acc[j][r] = 0.f;

    for (int k0 = 0; k0 < Hdim; k0 += KC) {
        // stage W tile: 128 rows x 64 k  (2048 float4, 8 per thread)
#pragma unroll
        for (int s = 0; s < 8; s++) {
            int idx = tid + 256 * s;
            int vv = idx >> 4, kk4 = idx & 15;
            float4 w4 = *(const float4*)(w_out + (size_t)(vb + vv) * Hdim + k0 + kk4 * 4);
            *(float4*)(&Ws[vv][kk4 * 4]) = w4;
        }
        // stage A tile: 64 rows x 64 k (1024 float4, 4 per thread)
#pragma unroll
        for (int s = 0; s < 4; s++) {
            int idx = tid + 256 * s;
            int bb = idx >> 4, kk4 = idx & 15;
            float4 a4 = *(const float4*)(hin + (size_t)bb * hstride + k0 + kk4 * 4);
            *(float4*)(&As[bb][kk4 * 4]) = a4;
        }
        __syncthreads();
#pragma unroll
        for (int kk = 0; kk < KC; kk += 4) {
            float4 a4[4], w4[8];
#pragma unroll
            for (int j = 0; j < 4; j++) a4[j] = *(const float4*)(&As[ty * 4 + j][kk]);
#pragma unroll
            for (int r = 0; r < 8; r++) w4[r] = *(const float4*)(&Ws[tx + 16 * r][kk]);
#pragma unroll
            for (int j = 0; j < 4; j++)
#pragma unroll
                for (int r = 0; r < 8; r++) {
                    acc[j][r] += a4[j].x * w4[r].x;
                    acc[j][r] += a4[j].y * w4[r].y;
                    acc[j][r] += a4[j].z * w4[r].z;
                    acc[j][r] += a4[j].w * w4[r].w;
                }
        }
        __syncthreads();
    }

    // epilogue: bias, store, argmax
    float bo[8];
#pragma unroll
    for (int r = 0; r < 8; r++) bo[r] = b_out[vb + tx + 16 * r];

    unsigned long long local_key[4];
#pragma unroll
    for (int j = 0; j < 4; j++) {
        int b = ty * 4 + j;
        float* orow = dec_out + ((size_t)(b * Tdim + t_out)) * Vdim + vb;
        unsigned long long best = 0ull;
#pragma unroll
        for (int r = 0; r < 8; r++) {
            float val = acc[j][r] + bo[r];
            orow[tx + 16 * r] = val;
            unsigned long long key = pack_key(val, vb + tx + 16 * r);
            if (key > best) best = key;
        }
        local_key[j] = best;
    }

    if (do_argmax) {
#pragma unroll
        for (int j = 0; j < 4; j++) red[tid][j] = local_key[j];
        __syncthreads();
        if (tid < 64) {
            int b = tid;
            int jj = b & 3, tyy = b >> 2;
            unsigned long long best = 0ull;
#pragma unroll
            for (int t2 = 0; t2 < 16; t2++) {
                unsigned long long key = red[tyy * 16 + t2][jj];
                if (key > best) best = key;
            }
            atomicMax(&slots[b], best);
        }
    }
}

// gates partial: out[b][n] = sum_{k in slice} xh[b*2048 + a_off + k] * W[n*H + k]
// tile: 32 n x 64 b, K-slice selected by blockIdx.y (0: x/w_ih -> gx, 1: h/w_hh -> gh)
__global__ __launch_bounds__(256, 2)
void k_gates(const float* __restrict__ xh,
             const float* __restrict__ w_ih, const float* __restrict__ w_hh,
             float* __restrict__ gx, float* __restrict__ gh)
{
    __shared__ float Ws[32][68];
    __shared__ float As[64][68];

    const int tid = threadIdx.x;
    const int tx = tid & 15;
    const int ty = tid >> 4;
    const int nb = blockIdx.x * 32;
    const int ky = blockIdx.y;
    const float* __restrict__ W = ky ? w_hh : w_ih;
    float* __restrict__ out = ky ? gh : gx;
    const int a_off = ky * Hdim;

    float acc[4][2];
#pragma unroll
    for (int j = 0; j < 4; j++) { acc[j][0] = 0.f; acc[j][1] = 0.f; }

    for (int k0 = 0; k0 < Hdim; k0 += KC) {
        // W tile 32x64 = 512 float4, 2 per thread
#pragma unroll
        for (int s = 0; s < 2; s++) {
            int idx = tid + 256 * s;
            int vv = idx >> 4, kk4 = idx & 15;
            float4 w4 = *(const float4*)(W + (size_t)(nb + vv) * Hdim + k0 + kk4 * 4);
            *(float4*)(&Ws[vv][kk4 * 4]) = w4;
        }
        // A tile 64x64, 4 per thread (xh row stride 2048)
#pragma unroll
        for (int s = 0; s < 4; s++) {
            int idx = tid + 256 * s;
            int bb = idx >> 4, kk4 = idx & 15;
            float4 a4 = *(const float4*)(xh + (size_t)bb * 2048 + a_off + k0 + kk4 * 4);
            *(float4*)(&As[bb][kk4 * 4]) = a4;
        }
        __syncthreads();
#pragma unroll
        for (int kk = 0; kk < KC; kk += 4) {
            float4 a4[4], w4[2];
#pragma unroll
            for (int j = 0; j < 4; j++) a4[j] = *(const float4*)(&As[ty * 4 + j][kk]);
#pragma unroll
            for (int r = 0; r < 2; r++) w4[r] = *(const float4*)(&Ws[tx + 16 * r][kk]);
#pragma unroll
            for (int j = 0; j < 4; j++)
#pragma unroll
                for (int r = 0; r < 2; r++) {
                    acc[j][r] += a4[j].x * w4[r].x;
                    acc[j][r] += a4[j].y * w4[r].y;
                    acc[j][r] += a4[j].z * w4[r].z;
                    acc[j][r] += a4[j].w * w4[r].w;
                }
        }
        __syncthreads();
    }
#pragma unroll
    for (int j = 0; j < 4; j++)
#pragma unroll
        for (int r = 0; r < 2; r++)
            out[(size_t)(ty * 4 + j) * 4096 + nb + tx + 16 * r] = acc[j][r];
}

// LSTM elementwise: gates = gx + gh + b_ih + b_hh (fixed order, deterministic)
__global__ void k_cell(const float* __restrict__ gx, const float* __restrict__ gh,
                       const float* __restrict__ b_ih, const float* __restrict__ b_hh,
                       float* __restrict__ cbuf, float* __restrict__ xh,
                       unsigned long long* __restrict__ slots)
{
    int idx = blockIdx.x * 256 + threadIdx.x;   // 0..65535
    int b = idx >> 10, k = idx & 1023;
    const int G = 4096;
    size_t base = (size_t)b * G;
    float gi = gx[base + k]        + gh[base + k]        + b_ih[k]        + b_hh[k];
    float gf = gx[base + 1024 + k] + gh[base + 1024 + k] + b_ih[1024 + k] + b_hh[1024 + k];
    float gg = gx[base + 2048 + k] + gh[base + 2048 + k] + b_ih[2048 + k] + b_hh[2048 + k];
    float go = gx[base + 3072 + k] + gh[base + 3072 + k] + b_ih[3072 + k] + b_hh[3072 + k];
    float si = 1.f / (1.f + expf(-gi));
    float sf = 1.f / (1.f + expf(-gf));
    float so = 1.f / (1.f + expf(-go));
    float c  = cbuf[idx];
    float c2 = sf * c + si * tanhf(gg);
    float h2 = so * tanhf(c2);
    cbuf[idx] = c2;
    xh[(size_t)b * 2048 + 1024 + k] = h2;
    if (idx < 64) slots[idx] = 0ull;   // reset argmax slots for upcoming k_logits
}

// decode argmax slot -> symbol, write to output tail, gather embedding row into xh
__global__ void k_symgather(const unsigned long long* __restrict__ slots,
                            const float* __restrict__ embed,
                            float* __restrict__ xh, float* __restrict__ sym_out, int t)
{
    __shared__ int s_sym;
    int b = blockIdx.x;
    if (threadIdx.x == 0) {
        unsigned long long key = slots[b];
        int v = (int)(0xFFFFFFFFu - (unsigned)(key & 0xFFFFFFFFull));
        s_sym = v;
        sym_out[b * Tdim + t] = (float)v;
    }
    __syncthreads();
    int v = s_sym;
    float4 e = *(const float4*)(embed + (size_t)v * Hdim + threadIdx.x * 4);
    *(float4*)(xh + (size_t)b * 2048 + threadIdx.x * 4) = e;
}

// initial state: sym = SOS(=1), x = embed[1], h = h0, c = c0
__global__ void k_init(const float* __restrict__ embed, const float* __restrict__ h0,
                       const float* __restrict__ c0, float* __restrict__ xh,
                       float* __restrict__ cbuf, float* __restrict__ sym_out)
{
    int b = blockIdx.x, t = threadIdx.x;
    if (t == 0) sym_out[b * Tdim + 0] = 1.0f;
    float4 e = *(const float4*)(embed + (size_t)1 * Hdim + t * 4);
    *(float4*)(xh + (size_t)b * 2048 + t * 4) = e;
    float4 h = *(const float4*)(h0 + (size_t)b * Hdim + t * 4);
    *(float4*)(xh + (size_t)b * 2048 + 1024 + t * 4) = h;
    float4 c = *(const float4*)(c0 + (size_t)b * Hdim + t * 4);
    *(float4*)(cbuf + (size_t)b * Hdim + t * 4) = c;
}

extern "C" void kernel_launch(void* const* d_in, const int* in_sizes, int n_in,
                              void* d_out, int out_size, void* d_ws, size_t ws_size,
                              hipStream_t stream)
{
    // setup_inputs order:
    // 0 output (unused), 1 h0, 2 c0, 3 target_outputs (unused), 4 target_lengths (unused),
    // 5 embed, 6 w_ih, 7 w_hh, 8 b_ih, 9 b_hh, 10 w_out, 11 b_out
    const float* h0    = (const float*)d_in[1];
    const float* c0    = (const float*)d_in[2];
    const float* embed = (const float*)d_in[5];
    const float* w_ih  = (const float*)d_in[6];
    const float* w_hh  = (const float*)d_in[7];
    const float* b_ih  = (const float*)d_in[8];
    const float* b_hh  = (const float*)d_in[9];
    const float* w_out = (const float*)d_in[10];
    const float* b_out = (const float*)d_in[11];

    float* out = (float*)d_out;                       // [B][T][V] then [B][T] symbols (as f32)
    float* sym_out = out + (size_t)Bdim * Tdim * Vdim;

    float* xh   = (float*)d_ws;                       // [64][2048]  (x | h)
    float* cbuf = xh + Bdim * 2048;                   // [64][1024]
    float* gx   = cbuf + Bdim * Hdim;                 // [64][4096]
    float* gh   = gx + Bdim * 4096;                   // [64][4096]
    unsigned long long* slots = (unsigned long long*)(gh + Bdim * 4096); // [64]

    k_init<<<Bdim, 256, 0, stream>>>(embed, h0, c0, xh, cbuf, sym_out);

    // decs[0] = embed[SOS] @ w_out.T + b_out  (identical for all b: stride 0)
    k_logits<<<Vdim / 128, 256, 0, stream>>>(embed + Hdim, 0, w_out, b_out, out, 0, slots, 0);

    for (int t = 0; t < Tdim - 1; t++) {
        k_gates<<<dim3(4096 / 32, 2), 256, 0, stream>>>(xh, w_ih, w_hh, gx, gh);
        k_cell<<<Bdim * Hdim / 256, 256, 0, stream>>>(gx, gh, b_ih, b_hh, cbuf, xh, slots);
        k_logits<<<Vdim / 128, 256, 0, stream>>>(xh + 1024, 2048, w_out, b_out, out, t + 1, slots, 1);
        k_symgather<<<Bdim, 256, 0, stream>>>(slots, embed, xh, sym_out, t + 1);
    }
}

// Round 2
// 5606.368 us; speedup vs baseline: 1.0866x; 1.0866x over previous
//
#include <hip/hip_runtime.h>

#define Bdim 64
#define Hdim 1024
#define Vdim 32000
#define Tdim 40
#define KC 64

// Order-preserving float->uint32 map; pack with (0xFFFFFFFF - v) so that
// u64 max == (max value, lowest index on exact ties) — matches np.argmax.
__device__ __forceinline__ unsigned long long pack_key(float f, int v) {
    unsigned u = __float_as_uint(f);
    u = (u & 0x80000000u) ? ~u : (u | 0x80000000u);
    return ((unsigned long long)u << 32) | (unsigned long long)(0xFFFFFFFFu - (unsigned)v);
}

// C[b][v] = sum_k hin[b*hstride + k] * w_out[v*H + k] + b_out[v]
// tile: 64 v x 64 b per block, 256 threads, micro-tile 4v x 4b.
// grid 500 -> ~2 blocks/CU resident (LDS 34.8 KB allows 4) for barrier overlap.
__global__ __launch_bounds__(256, 4)
void k_logits(const float* __restrict__ hin, int hstride,
              const float* __restrict__ w_out, const float* __restrict__ b_out,
              float* __restrict__ dec_out, int t_out,
              unsigned long long* __restrict__ slots, int do_argmax)
{
    __shared__ float Ws[64][68];
    __shared__ float As[64][68];

    const int tid = threadIdx.x;
    const int tx = tid & 15;        // v dimension (16 x 4 = 64 v)
    const int ty = tid >> 4;        // b dimension (16 x 4 = 64 b)
    const int vb = blockIdx.x * 64;

    float acc[4][4];
#pragma unroll
    for (int j = 0; j < 4; j++)
#pragma unroll
        for (int r = 0; r < 4; r++) acc[j][r] = 0.f;

    for (int k0 = 0; k0 < Hdim; k0 += KC) {
        // stage W tile: 64 rows x 64 k (1024 float4, 4 per thread)
#pragma unroll
        for (int s = 0; s < 4; s++) {
            int idx = tid + 256 * s;
            int vv = idx >> 4, kk4 = idx & 15;
            float4 w4 = *(const float4*)(w_out + (size_t)(vb + vv) * Hdim + k0 + kk4 * 4);
            *(float4*)(&Ws[vv][kk4 * 4]) = w4;
        }
        // stage A tile: 64 rows x 64 k (1024 float4, 4 per thread)
#pragma unroll
        for (int s = 0; s < 4; s++) {
            int idx = tid + 256 * s;
            int bb = idx >> 4, kk4 = idx & 15;
            float4 a4 = *(const float4*)(hin + (size_t)bb * hstride + k0 + kk4 * 4);
            *(float4*)(&As[bb][kk4 * 4]) = a4;
        }
        __syncthreads();
#pragma unroll
        for (int kk = 0; kk < KC; kk += 4) {
            float4 a4[4], w4[4];
#pragma unroll
            for (int j = 0; j < 4; j++) a4[j] = *(const float4*)(&As[ty * 4 + j][kk]);
#pragma unroll
            for (int r = 0; r < 4; r++) w4[r] = *(const float4*)(&Ws[tx + 16 * r][kk]);
#pragma unroll
            for (int j = 0; j < 4; j++)
#pragma unroll
                for (int r = 0; r < 4; r++) {
                    acc[j][r] += a4[j].x * w4[r].x;
                    acc[j][r] += a4[j].y * w4[r].y;
                    acc[j][r] += a4[j].z * w4[r].z;
                    acc[j][r] += a4[j].w * w4[r].w;
                }
        }
        __syncthreads();
    }

    // epilogue: bias, store, argmax
    float bo[4];
#pragma unroll
    for (int r = 0; r < 4; r++) bo[r] = b_out[vb + tx + 16 * r];

    unsigned long long local_key[4];
#pragma unroll
    for (int j = 0; j < 4; j++) {
        int b = ty * 4 + j;
        float* orow = dec_out + ((size_t)(b * Tdim + t_out)) * Vdim + vb;
        unsigned long long best = 0ull;
#pragma unroll
        for (int r = 0; r < 4; r++) {
            float val = acc[j][r] + bo[r];
            orow[tx + 16 * r] = val;
            unsigned long long key = pack_key(val, vb + tx + 16 * r);
            if (key > best) best = key;
        }
        local_key[j] = best;
    }

    if (do_argmax) {
        // As tile is dead after the final k-loop __syncthreads(); reuse as scratch.
        unsigned long long* red = (unsigned long long*)&As[0][0];  // [256][4]
#pragma unroll
        for (int j = 0; j < 4; j++) red[tid * 4 + j] = local_key[j];
        __syncthreads();
        if (tid < 64) {
            int b = tid;
            int jj = b & 3, tyy = b >> 2;
            unsigned long long best = 0ull;
#pragma unroll
            for (int t2 = 0; t2 < 16; t2++) {
                unsigned long long key = red[(tyy * 16 + t2) * 4 + jj];
                if (key > best) best = key;
            }
            atomicMax(&slots[b], best);
        }
    }
}

// gates partial: gp[y*2+z][b][n] = sum_{k in half z} xh[b*2048 + y*1024 + k] * W_y[n*H + k]
// tile: 32 n x 64 b x 512 k, grid (128, 2, 2) = 512 blocks (~2/CU).
__global__ __launch_bounds__(256, 4)
void k_gates(const float* __restrict__ xh,
             const float* __restrict__ w_ih, const float* __restrict__ w_hh,
             float* __restrict__ gp)
{
    __shared__ float Ws[32][68];
    __shared__ float As[64][68];

    const int tid = threadIdx.x;
    const int tx = tid & 15;
    const int ty = tid >> 4;
    const int nb = blockIdx.x * 32;
    const int y = blockIdx.y;       // 0: x/w_ih, 1: h/w_hh
    const int z = blockIdx.z;       // k half
    const float* __restrict__ W = y ? w_hh : w_ih;
    float* __restrict__ out = gp + (size_t)(y * 2 + z) * (Bdim * 4096);
    const int a_off = y * Hdim;
    const int kbeg = z * 512, kend = kbeg + 512;

    float acc[4][2];
#pragma unroll
    for (int j = 0; j < 4; j++) { acc[j][0] = 0.f; acc[j][1] = 0.f; }

    for (int k0 = kbeg; k0 < kend; k0 += KC) {
        // W tile 32x64 = 512 float4, 2 per thread
#pragma unroll
        for (int s = 0; s < 2; s++) {
            int idx = tid + 256 * s;
            int vv = idx >> 4, kk4 = idx & 15;
            float4 w4 = *(const float4*)(W + (size_t)(nb + vv) * Hdim + k0 + kk4 * 4);
            *(float4*)(&Ws[vv][kk4 * 4]) = w4;
        }
        // A tile 64x64, 4 per thread (xh row stride 2048)
#pragma unroll
        for (int s = 0; s < 4; s++) {
            int idx = tid + 256 * s;
            int bb = idx >> 4, kk4 = idx & 15;
            float4 a4 = *(const float4*)(xh + (size_t)bb * 2048 + a_off + k0 + kk4 * 4);
            *(float4*)(&As[bb][kk4 * 4]) = a4;
        }
        __syncthreads();
#pragma unroll
        for (int kk = 0; kk < KC; kk += 4) {
            float4 a4[4], w4[2];
#pragma unroll
            for (int j = 0; j < 4; j++) a4[j] = *(const float4*)(&As[ty * 4 + j][kk]);
#pragma unroll
            for (int r = 0; r < 2; r++) w4[r] = *(const float4*)(&Ws[tx + 16 * r][kk]);
#pragma unroll
            for (int j = 0; j < 4; j++)
#pragma unroll
                for (int r = 0; r < 2; r++) {
                    acc[j][r] += a4[j].x * w4[r].x;
                    acc[j][r] += a4[j].y * w4[r].y;
                    acc[j][r] += a4[j].z * w4[r].z;
                    acc[j][r] += a4[j].w * w4[r].w;
                }
        }
        __syncthreads();
    }
#pragma unroll
    for (int j = 0; j < 4; j++)
#pragma unroll
        for (int r = 0; r < 2; r++)
            out[(size_t)(ty * 4 + j) * 4096 + nb + tx + 16 * r] = acc[j][r];
}

// LSTM elementwise: gates = gp0 + gp1 + gp2 + gp3 + b_ih + b_hh (fixed order, deterministic)
__global__ void k_cell(const float* __restrict__ gp,
                       const float* __restrict__ b_ih, const float* __restrict__ b_hh,
                       float* __restrict__ cbuf, float* __restrict__ xh,
                       unsigned long long* __restrict__ slots)
{
    int idx = blockIdx.x * 256 + threadIdx.x;   // 0..65535
    int b = idx >> 10, k = idx & 1023;
    size_t base = (size_t)b * 4096;
    const size_t S = (size_t)Bdim * 4096;
    float g[4];
#pragma unroll
    for (int q = 0; q < 4; q++) {
        size_t o = base + q * 1024 + k;
        g[q] = gp[o] + gp[S + o] + gp[2 * S + o] + gp[3 * S + o]
             + b_ih[q * 1024 + k] + b_hh[q * 1024 + k];
    }
    float si = 1.f / (1.f + expf(-g[0]));
    float sf = 1.f / (1.f + expf(-g[1]));
    float so = 1.f / (1.f + expf(-g[3]));
    float c  = cbuf[idx];
    float c2 = sf * c + si * tanhf(g[2]);
    float h2 = so * tanhf(c2);
    cbuf[idx] = c2;
    xh[(size_t)b * 2048 + 1024 + k] = h2;
    if (idx < 64) slots[idx] = 0ull;   // reset argmax slots for upcoming k_logits
}

// decode argmax slot -> symbol, write to output tail, gather embedding row into xh
__global__ void k_symgather(const unsigned long long* __restrict__ slots,
                            const float* __restrict__ embed,
                            float* __restrict__ xh, float* __restrict__ sym_out, int t)
{
    __shared__ int s_sym;
    int b = blockIdx.x;
    if (threadIdx.x == 0) {
        unsigned long long key = slots[b];
        int v = (int)(0xFFFFFFFFu - (unsigned)(key & 0xFFFFFFFFull));
        s_sym = v;
        sym_out[b * Tdim + t] = (float)v;
    }
    __syncthreads();
    int v = s_sym;
    float4 e = *(const float4*)(embed + (size_t)v * Hdim + threadIdx.x * 4);
    *(float4*)(xh + (size_t)b * 2048 + threadIdx.x * 4) = e;
}

// initial state: sym = SOS(=1), x = embed[1], h = h0, c = c0
__global__ void k_init(const float* __restrict__ embed, const float* __restrict__ h0,
                       const float* __restrict__ c0, float* __restrict__ xh,
                       float* __restrict__ cbuf, float* __restrict__ sym_out)
{
    int b = blockIdx.x, t = threadIdx.x;
    if (t == 0) sym_out[b * Tdim + 0] = 1.0f;
    float4 e = *(const float4*)(embed + (size_t)1 * Hdim + t * 4);
    *(float4*)(xh + (size_t)b * 2048 + t * 4) = e;
    float4 h = *(const float4*)(h0 + (size_t)b * Hdim + t * 4);
    *(float4*)(xh + (size_t)b * 2048 + 1024 + t * 4) = h;
    float4 c = *(const float4*)(c0 + (size_t)b * Hdim + t * 4);
    *(float4*)(cbuf + (size_t)b * Hdim + t * 4) = c;
}

extern "C" void kernel_launch(void* const* d_in, const int* in_sizes, int n_in,
                              void* d_out, int out_size, void* d_ws, size_t ws_size,
                              hipStream_t stream)
{
    // setup_inputs order:
    // 0 output (unused), 1 h0, 2 c0, 3 target_outputs (unused), 4 target_lengths (unused),
    // 5 embed, 6 w_ih, 7 w_hh, 8 b_ih, 9 b_hh, 10 w_out, 11 b_out
    const float* h0    = (const float*)d_in[1];
    const float* c0    = (const float*)d_in[2];
    const float* embed = (const float*)d_in[5];
    const float* w_ih  = (const float*)d_in[6];
    const float* w_hh  = (const float*)d_in[7];
    const float* b_ih  = (const float*)d_in[8];
    const float* b_hh  = (const float*)d_in[9];
    const float* w_out = (const float*)d_in[10];
    const float* b_out = (const float*)d_in[11];

    float* out = (float*)d_out;                       // [B][T][V] then [B][T] symbols (as f32)
    float* sym_out = out + (size_t)Bdim * Tdim * Vdim;

    float* xh   = (float*)d_ws;                       // [64][2048]  (x | h)
    float* cbuf = xh + Bdim * 2048;                   // [64][1024]
    float* gp   = cbuf + Bdim * Hdim;                 // [4][64][4096] partials
    unsigned long long* slots = (unsigned long long*)(gp + 4 * (size_t)Bdim * 4096); // [64]

    k_init<<<Bdim, 256, 0, stream>>>(embed, h0, c0, xh, cbuf, sym_out);

    // decs[0] = embed[SOS] @ w_out.T + b_out  (identical for all b: stride 0)
    k_logits<<<Vdim / 64, 256, 0, stream>>>(embed + Hdim, 0, w_out, b_out, out, 0, slots, 0);

    for (int t = 0; t < Tdim - 1; t++) {
        k_gates<<<dim3(4096 / 32, 2, 2), 256, 0, stream>>>(xh, w_ih, w_hh, gp);
        k_cell<<<Bdim * Hdim / 256, 256, 0, stream>>>(gp, b_ih, b_hh, cbuf, xh, slots);
        k_logits<<<Vdim / 64, 256, 0, stream>>>(xh + 1024, 2048, w_out, b_out, out, t + 1, slots, 1);
        k_symgather<<<Bdim, 256, 0, stream>>>(slots, embed, xh, sym_out, t + 1);
    }
}